// Round 1
// baseline (381.517 us; speedup 1.0000x reference)
//
#include <hip/hip_runtime.h>
#include <hip/hip_bf16.h>

#define B_ 2
#define C_ 512
#define HW_ 4096
#define K_ 512
#define EPS_ 1e-6f
#define SCALE_ 0.04419417382415922f   // 512^-0.5
#define NEG_INF_ (-1e30f)

typedef __attribute__((ext_vector_type(8))) __bf16 bf16x8;
typedef __attribute__((ext_vector_type(4))) float f32x4;

__device__ __forceinline__ unsigned short f2bf(float f) {
  union { float f; unsigned u; } v; v.f = f;
  unsigned r = v.u + 0x7fffu + ((v.u >> 16) & 1u);
  return (unsigned short)(r >> 16);
}

// ---------------- GroupNorm stats: one block per (b, group) ----------------
__global__ void gn_stats(const float* __restrict__ x, float* __restrict__ stats) {
  int bg = blockIdx.x;            // b*32 + g
  int b = bg >> 5, g = bg & 31;
  const float* base = x + ((size_t)(b * C_ + g * 16)) * HW_;
  float s = 0.f, s2 = 0.f;
  int t = threadIdx.x;
  for (int it = 0; it < 64; ++it) {          // 16 rows * 1024 float4
    int flat = t + it * 256;
    int row = flat >> 10, col = (flat & 1023) << 2;
    float4 v = *reinterpret_cast<const float4*>(base + (size_t)row * HW_ + col);
    s  += v.x + v.y + v.z + v.w;
    s2 += v.x * v.x + v.y * v.y + v.z * v.z + v.w * v.w;
  }
  for (int off = 32; off; off >>= 1) { s += __shfl_down(s, off); s2 += __shfl_down(s2, off); }
  __shared__ float rs[4], rs2[4];
  int w = t >> 6;
  if ((t & 63) == 0) { rs[w] = s; rs2[w] = s2; }
  __syncthreads();
  if (t == 0) {
    float S = rs[0] + rs[1] + rs[2] + rs[3];
    float S2 = rs2[0] + rs2[1] + rs2[2] + rs2[3];
    float mean = S * (1.f / 65536.f);
    float var = S2 * (1.f / 65536.f) - mean * mean;
    stats[bg] = mean;
    stats[64 + bg] = rsqrtf(var + EPS_);
  }
}

// ------------- normalize + transpose: x(b,c,n) f32 -> t(b,n,c) bf16 -------------
__global__ void build_t(const float* __restrict__ x, const float* __restrict__ stats,
                        const float* __restrict__ gamma, const float* __restrict__ beta,
                        unsigned short* __restrict__ tb) {
  __shared__ float lds[64 * 69];
  int n0 = blockIdx.x * 64, c0 = blockIdx.y * 64, b = blockIdx.z;
  int t = threadIdx.x;
  {
    int cl = t >> 2, ch = t & 3;
    int c = c0 + cl;
    int bg = b * 32 + (c >> 4);
    float rstd = stats[64 + bg];
    float ga = gamma[c] * rstd;
    float be = beta[c] - stats[bg] * ga;
    const float* xr = x + ((size_t)(b * C_ + c)) * HW_ + n0 + ch * 16;
    #pragma unroll
    for (int i = 0; i < 4; ++i) {
      float4 v = *reinterpret_cast<const float4*>(xr + i * 4);
      int nl = ch * 16 + i * 4;
      lds[cl * 69 + nl + 0] = v.x * ga + be;
      lds[cl * 69 + nl + 1] = v.y * ga + be;
      lds[cl * 69 + nl + 2] = v.z * ga + be;
      lds[cl * 69 + nl + 3] = v.w * ga + be;
    }
  }
  __syncthreads();
  {
    int nl = t >> 2, cw = t & 3;
    unsigned short* orow = tb + ((size_t)(b * HW_ + n0 + nl)) * C_ + c0 + cw * 16;
    #pragma unroll
    for (int i = 0; i < 4; ++i) {
      ushort4 o4;
      o4.x = f2bf(lds[(cw * 16 + i * 4 + 0) * 69 + nl]);
      o4.y = f2bf(lds[(cw * 16 + i * 4 + 1) * 69 + nl]);
      o4.z = f2bf(lds[(cw * 16 + i * 4 + 2) * 69 + nl]);
      o4.w = f2bf(lds[(cw * 16 + i * 4 + 3) * 69 + nl]);
      *reinterpret_cast<ushort4*>(orow + i * 4) = o4;
    }
  }
}

// ---------------- f32 -> bf16 weight cast ----------------
__global__ void cast_w(const float* __restrict__ src, unsigned short* __restrict__ dst) {
  int i = (blockIdx.x * 256 + threadIdx.x) * 4;
  float4 v = *reinterpret_cast<const float4*>(src + i);
  ushort4 o; o.x = f2bf(v.x); o.y = f2bf(v.y); o.z = f2bf(v.z); o.w = f2bf(v.w);
  *reinterpret_cast<ushort4*>(dst + i) = o;
}

// ---------------- C[m][n] = sum_k A[m][k] B[n][k]  (both row-major over k) ----------------
// MODE 0: bf16 out, bias per col (q,k).  MODE 1: bf16 out, bias per row (vT).
// MODE 2: f32 out, bias per row + residual (final proj).
template <int MODE>
__global__ __launch_bounds__(256, 2) void gemm_bt(
    const unsigned short* __restrict__ A, long sA,
    const unsigned short* __restrict__ B, long sB,
    void* __restrict__ Cv, long sC, int M, int N,
    const float* __restrict__ bias,
    const float* __restrict__ resid, long sR) {
  __shared__ unsigned short Al[128 * 72];
  __shared__ unsigned short Bl[128 * 72];
  int z = blockIdx.z;
  const unsigned short* Ab = A + (size_t)z * sA;
  const unsigned short* Bb = B + (size_t)z * sB;
  int n0 = blockIdx.x * 128, m0 = blockIdx.y * 128;
  int t = threadIdx.x, lane = t & 63, w = t >> 6;
  int l15 = lane & 15, quad = lane >> 4;
  int mw = (w & 1) * 64, nw = (w >> 1) * 64;
  f32x4 acc[4][4] = {};
  int r = t >> 1, coff = (t & 1) * 32;
  for (int kc = 0; kc < K_; kc += 64) {
    __syncthreads();
    const unsigned short* As = Ab + (size_t)(m0 + r) * K_ + kc + coff;
    const unsigned short* Bs = Bb + (size_t)(n0 + r) * K_ + kc + coff;
    #pragma unroll
    for (int i = 0; i < 4; ++i) {
      *reinterpret_cast<uint4*>(&Al[r * 72 + coff + i * 8]) = *reinterpret_cast<const uint4*>(As + i * 8);
      *reinterpret_cast<uint4*>(&Bl[r * 72 + coff + i * 8]) = *reinterpret_cast<const uint4*>(Bs + i * 8);
    }
    __syncthreads();
    #pragma unroll
    for (int kk = 0; kk < 2; ++kk) {
      bf16x8 af[4];
      #pragma unroll
      for (int mt = 0; mt < 4; ++mt)
        af[mt] = *reinterpret_cast<const bf16x8*>(&Al[(mw + mt * 16 + l15) * 72 + kk * 32 + quad * 8]);
      #pragma unroll
      for (int nt = 0; nt < 4; ++nt) {
        bf16x8 bfr = *reinterpret_cast<const bf16x8*>(&Bl[(nw + nt * 16 + l15) * 72 + kk * 32 + quad * 8]);
        #pragma unroll
        for (int mt = 0; mt < 4; ++mt)
          acc[mt][nt] = __builtin_amdgcn_mfma_f32_16x16x32_bf16(af[mt], bfr, acc[mt][nt], 0, 0, 0);
      }
    }
  }
  #pragma unroll
  for (int mt = 0; mt < 4; ++mt)
    #pragma unroll
    for (int nt = 0; nt < 4; ++nt)
      #pragma unroll
      for (int rr = 0; rr < 4; ++rr) {
        int row = m0 + mw + mt * 16 + quad * 4 + rr;
        int col = n0 + nw + nt * 16 + l15;
        float v = acc[mt][nt][rr];
        if (MODE == 0) {
          v += bias[col];
          reinterpret_cast<unsigned short*>(Cv)[(size_t)z * sC + (size_t)row * N + col] = f2bf(v);
        } else if (MODE == 1) {
          v += bias[row];
          reinterpret_cast<unsigned short*>(Cv)[(size_t)z * sC + (size_t)row * N + col] = f2bf(v);
        } else {
          v += bias[row];
          v += resid[(size_t)z * sR + (size_t)row * N + col];
          reinterpret_cast<float*>(Cv)[(size_t)z * sC + (size_t)row * N + col] = v;
        }
      }
}

// ---------------- flash attention: Br=64, Bc=128, j-split 2 ----------------
__global__ __launch_bounds__(512, 2) void attn(
    const unsigned short* __restrict__ qg, const unsigned short* __restrict__ kg,
    const unsigned short* __restrict__ vg,  // vT: (b, c, n)
    float* __restrict__ opart, float* __restrict__ mpart, float* __restrict__ lpart) {
  __shared__ unsigned short KVl[128 * 136];
  __shared__ unsigned short Pl[64 * 136];
  __shared__ float sm_m[64], sm_l[64], sm_alpha[64], sm_red[128];
  int qt = blockIdx.x, jh = blockIdx.y, b = blockIdx.z;
  int t = threadIdx.x, lane = t & 63, w = t >> 6;
  int l15 = lane & 15, quad = lane >> 4;
  int rw = w & 3, cw = w >> 2;
  int m0 = qt * 64;
  if (t < 64) { sm_m[t] = NEG_INF_; sm_l[t] = 0.f; }
  bf16x8 qa[16];
  {
    const unsigned short* qrow = qg + ((size_t)(b * HW_ + m0 + rw * 16 + l15)) * K_ + quad * 8;
    #pragma unroll
    for (int kk = 0; kk < 16; ++kk)
      qa[kk] = *reinterpret_cast<const bf16x8*>(qrow + kk * 32);
  }
  f32x4 acc_o[4][4] = {};
  int sr = t >> 2, scoff = (t & 3) * 32;
  __syncthreads();
  for (int it = 0; it < 16; ++it) {
    int j0 = jh * 2048 + it * 128;
    f32x4 acc_s[4] = {};
    #pragma unroll
    for (int kc = 0; kc < 512; kc += 128) {
      __syncthreads();
      const unsigned short* ks = kg + ((size_t)(b * HW_ + j0 + sr)) * K_ + kc + scoff;
      #pragma unroll
      for (int i = 0; i < 4; ++i)
        *reinterpret_cast<uint4*>(&KVl[sr * 136 + scoff + i * 8]) = *reinterpret_cast<const uint4*>(ks + i * 8);
      __syncthreads();
      #pragma unroll
      for (int kk = 0; kk < 4; ++kk)
        #pragma unroll
        for (int ct = 0; ct < 4; ++ct) {
          bf16x8 bfr = *reinterpret_cast<const bf16x8*>(&KVl[(cw * 64 + ct * 16 + l15) * 136 + kk * 32 + quad * 8]);
          acc_s[ct] = __builtin_amdgcn_mfma_f32_16x16x32_bf16(qa[(kc >> 5) + kk], bfr, acc_s[ct], 0, 0, 0);
        }
    }
    // scale + row max (over this wave's 64 cols)
    float mx[4];
    #pragma unroll
    for (int rr = 0; rr < 4; ++rr) {
      float m = NEG_INF_;
      #pragma unroll
      for (int ct = 0; ct < 4; ++ct) {
        acc_s[ct][rr] *= SCALE_;
        m = fmaxf(m, acc_s[ct][rr]);
      }
      mx[rr] = m;
    }
    #pragma unroll
    for (int off = 1; off < 16; off <<= 1)
      #pragma unroll
      for (int rr = 0; rr < 4; ++rr)
        mx[rr] = fmaxf(mx[rr], __shfl_xor(mx[rr], off));
    if (l15 == 0)
      #pragma unroll
      for (int rr = 0; rr < 4; ++rr)
        sm_red[cw * 64 + rw * 16 + quad * 4 + rr] = mx[rr];
    __syncthreads();
    if (t < 64) {
      float mnew = fmaxf(sm_m[t], fmaxf(sm_red[t], sm_red[64 + t]));
      sm_alpha[t] = __expf(sm_m[t] - mnew);
      sm_m[t] = mnew;
    }
    __syncthreads();
    // P = exp(s - m) -> LDS (bf16) + row sums
    float sum[4] = {0.f, 0.f, 0.f, 0.f};
    #pragma unroll
    for (int ct = 0; ct < 4; ++ct)
      #pragma unroll
      for (int rr = 0; rr < 4; ++rr) {
        int rowl = rw * 16 + quad * 4 + rr;
        float p = __expf(acc_s[ct][rr] - sm_m[rowl]);
        sum[rr] += p;
        Pl[rowl * 136 + cw * 64 + ct * 16 + l15] = f2bf(p);
      }
    #pragma unroll
    for (int off = 1; off < 16; off <<= 1)
      #pragma unroll
      for (int rr = 0; rr < 4; ++rr)
        sum[rr] += __shfl_xor(sum[rr], off);
    if (l15 == 0)
      #pragma unroll
      for (int rr = 0; rr < 4; ++rr)
        sm_red[cw * 64 + rw * 16 + quad * 4 + rr] = sum[rr];
    __syncthreads();
    if (t < 64)
      sm_l[t] = sm_l[t] * sm_alpha[t] + sm_red[t] + sm_red[64 + t];
    // rescale O by alpha
    #pragma unroll
    for (int rr = 0; rr < 4; ++rr) {
      float a = sm_alpha[rw * 16 + quad * 4 + rr];
      #pragma unroll
      for (int dc = 0; dc < 4; ++dc)
        #pragma unroll
        for (int nt = 0; nt < 4; ++nt)
          acc_o[dc][nt][rr] *= a;
    }
    // P A-frags (constant across the dc loop)
    bf16x8 pa[4];
    #pragma unroll
    for (int ksx = 0; ksx < 4; ++ksx)
      pa[ksx] = *reinterpret_cast<const bf16x8*>(&Pl[(rw * 16 + l15) * 136 + ksx * 32 + quad * 8]);
    #pragma unroll
    for (int dc = 0; dc < 4; ++dc) {
      __syncthreads();
      const unsigned short* vs = vg + ((size_t)(b * K_ + dc * 128 + sr)) * HW_ + j0 + scoff;
      #pragma unroll
      for (int i = 0; i < 4; ++i)
        *reinterpret_cast<uint4*>(&KVl[sr * 136 + scoff + i * 8]) = *reinterpret_cast<const uint4*>(vs + i * 8);
      __syncthreads();
      #pragma unroll
      for (int nt = 0; nt < 4; ++nt)
        #pragma unroll
        for (int ksx = 0; ksx < 4; ++ksx) {
          bf16x8 vb = *reinterpret_cast<const bf16x8*>(&KVl[(cw * 64 + nt * 16 + l15) * 136 + ksx * 32 + quad * 8]);
          acc_o[dc][nt] = __builtin_amdgcn_mfma_f32_16x16x32_bf16(pa[ksx], vb, acc_o[dc][nt], 0, 0, 0);
        }
    }
  }
  // write partials (unnormalized O, running m and l)
  int part = jh * 2 + b;
  float* ob = opart + ((size_t)part * HW_ + m0) * 512;
  #pragma unroll
  for (int dc = 0; dc < 4; ++dc)
    #pragma unroll
    for (int nt = 0; nt < 4; ++nt) {
      int d = dc * 128 + cw * 64 + nt * 16 + l15;
      #pragma unroll
      for (int rr = 0; rr < 4; ++rr) {
        int rowl = rw * 16 + quad * 4 + rr;
        ob[(size_t)rowl * 512 + d] = acc_o[dc][nt][rr];
      }
    }
  __syncthreads();
  if (t < 64) {
    mpart[(size_t)part * HW_ + m0 + t] = sm_m[t];
    lpart[(size_t)part * HW_ + m0 + t] = sm_l[t];
  }
}

// ---------------- merge the two j-split halves ----------------
__global__ void merge_o(const float* __restrict__ opart, const float* __restrict__ mpart,
                        const float* __restrict__ lpart, unsigned short* __restrict__ om) {
  int rg = blockIdx.x;            // b*4096 + n
  int b = rg >> 12, n = rg & 4095;
  size_t r0 = (size_t)(0 * 2 + b) * HW_ + n;
  size_t r1 = (size_t)(1 * 2 + b) * HW_ + n;
  float m0v = mpart[r0], m1v = mpart[r1];
  float M = fmaxf(m0v, m1v);
  float w0 = __expf(m0v - M), w1 = __expf(m1v - M);
  float inv = 1.f / (lpart[r0] * w0 + lpart[r1] * w1);
  const float* a0 = opart + r0 * 512;
  const float* a1 = opart + r1 * 512;
  unsigned short* orow = om + (size_t)rg * 512;
  for (int d = threadIdx.x; d < 512; d += 256)
    orow[d] = f2bf((a0[d] * w0 + a1[d] * w1) * inv);
}

extern "C" void kernel_launch(void* const* d_in, const int* in_sizes, int n_in,
                              void* d_out, int out_size, void* d_ws, size_t ws_size,
                              hipStream_t stream) {
  const float* x     = (const float*)d_in[0];
  const float* gamma = (const float*)d_in[1];
  const float* beta  = (const float*)d_in[2];
  const float* wq    = (const float*)d_in[3];
  const float* bq    = (const float*)d_in[4];
  const float* wk    = (const float*)d_in[5];
  const float* bk    = (const float*)d_in[6];
  const float* wv    = (const float*)d_in[7];
  const float* bv    = (const float*)d_in[8];
  const float* wp    = (const float*)d_in[9];
  const float* bp    = (const float*)d_in[10];
  float* out = (float*)d_out;

  char* ws = (char*)d_ws;
  size_t o = 0;
  float* stats          = (float*)(ws + o);          o += 1024;
  unsigned short* tb    = (unsigned short*)(ws + o); o += 8388608;
  unsigned short* qb    = (unsigned short*)(ws + o); o += 8388608;
  unsigned short* kb    = (unsigned short*)(ws + o); o += 8388608;
  unsigned short* vTb   = (unsigned short*)(ws + o); o += 8388608;
  unsigned short* wqb   = (unsigned short*)(ws + o); o += 524288;
  unsigned short* wkb   = (unsigned short*)(ws + o); o += 524288;
  unsigned short* wvb   = (unsigned short*)(ws + o); o += 524288;
  unsigned short* wpb   = (unsigned short*)(ws + o); o += 524288;
  float* opart          = (float*)(ws + o);          o += 33554432;
  float* mpart          = (float*)(ws + o);          o += 65536;
  float* lpart          = (float*)(ws + o);          o += 65536;
  unsigned short* om    = (unsigned short*)(ws + o); o += 8388608;

  gn_stats<<<64, 256, 0, stream>>>(x, stats);
  build_t<<<dim3(64, 8, 2), 256, 0, stream>>>(x, stats, gamma, beta, tb);
  cast_w<<<256, 256, 0, stream>>>(wq, wqb);
  cast_w<<<256, 256, 0, stream>>>(wk, wkb);
  cast_w<<<256, 256, 0, stream>>>(wv, wvb);
  cast_w<<<256, 256, 0, stream>>>(wp, wpb);
  // q = t @ wq^T + bq  (M=4096 rows of t, N=512 outputs)
  gemm_bt<0><<<dim3(4, 32, 2), 256, 0, stream>>>(tb, (long)HW_ * K_, wqb, 0, qb, (long)HW_ * K_, HW_, C_, bq, nullptr, 0);
  gemm_bt<0><<<dim3(4, 32, 2), 256, 0, stream>>>(tb, (long)HW_ * K_, wkb, 0, kb, (long)HW_ * K_, HW_, C_, bk, nullptr, 0);
  // vT[o][n] = wv[o][:] . t[n][:] + bv[o]  (M=512, N=4096)
  gemm_bt<1><<<dim3(32, 4, 2), 256, 0, stream>>>(wvb, 0, tb, (long)HW_ * K_, vTb, (long)C_ * HW_, C_, HW_, bv, nullptr, 0);
  attn<<<dim3(64, 2, 2), 512, 0, stream>>>(qb, kb, vTb, opart, mpart, lpart);
  merge_o<<<8192, 256, 0, stream>>>(opart, mpart, lpart, om);
  // out[c][n] = x + wp[c][:] . o[n][:] + bp[c]
  gemm_bt<2><<<dim3(32, 4, 2), 256, 0, stream>>>(wpb, 0, om, (long)HW_ * K_, out, (long)C_ * HW_, C_, HW_, bp, x, (long)C_ * HW_);
}

// Round 2
// 378.898 us; speedup vs baseline: 1.0069x; 1.0069x over previous
//
#include <hip/hip_runtime.h>
#include <hip/hip_bf16.h>

#define B_ 2
#define C_ 512
#define HW_ 4096
#define K_ 512
#define EPS_ 1e-6f
#define SCALE_ 0.04419417382415922f   // 512^-0.5
#define NEG_INF_ (-1e30f)

typedef __attribute__((ext_vector_type(8))) __bf16 bf16x8;
typedef __attribute__((ext_vector_type(4))) float f32x4;

__device__ __forceinline__ unsigned short f2bf(float f) {
  union { float f; unsigned u; } v; v.f = f;
  unsigned r = v.u + 0x7fffu + ((v.u >> 16) & 1u);
  return (unsigned short)(r >> 16);
}
__device__ __forceinline__ float bf2f(unsigned short h) {
  union { unsigned u; float f; } v; v.u = ((unsigned)h) << 16;
  return v.f;
}

// ---------------- GroupNorm stats: one block per (b, group) ----------------
__global__ void gn_stats(const float* __restrict__ x, float* __restrict__ stats) {
  int bg = blockIdx.x;            // b*32 + g
  int b = bg >> 5, g = bg & 31;
  const float* base = x + ((size_t)(b * C_ + g * 16)) * HW_;
  float s = 0.f, s2 = 0.f;
  int t = threadIdx.x;
  for (int it = 0; it < 64; ++it) {          // 16 rows * 1024 float4
    int flat = t + it * 256;
    int row = flat >> 10, col = (flat & 1023) << 2;
    float4 v = *reinterpret_cast<const float4*>(base + (size_t)row * HW_ + col);
    s  += v.x + v.y + v.z + v.w;
    s2 += v.x * v.x + v.y * v.y + v.z * v.z + v.w * v.w;
  }
  for (int off = 32; off; off >>= 1) { s += __shfl_down(s, off); s2 += __shfl_down(s2, off); }
  __shared__ float rs[4], rs2[4];
  int w = t >> 6;
  if ((t & 63) == 0) { rs[w] = s; rs2[w] = s2; }
  __syncthreads();
  if (t == 0) {
    float S = rs[0] + rs[1] + rs[2] + rs[3];
    float S2 = rs2[0] + rs2[1] + rs2[2] + rs2[3];
    float mean = S * (1.f / 65536.f);
    float var = S2 * (1.f / 65536.f) - mean * mean;
    stats[bg] = mean;
    stats[64 + bg] = rsqrtf(var + EPS_);
  }
}

// ------------- normalize + transpose: x(b,c,n) f32 -> t(b,n,c) bf16 -------------
__global__ void build_t(const float* __restrict__ x, const float* __restrict__ stats,
                        const float* __restrict__ gamma, const float* __restrict__ beta,
                        unsigned short* __restrict__ tb) {
  __shared__ float lds[64 * 69];
  int n0 = blockIdx.x * 64, c0 = blockIdx.y * 64, b = blockIdx.z;
  int t = threadIdx.x;
  {
    int cl = t >> 2, ch = t & 3;
    int c = c0 + cl;
    int bg = b * 32 + (c >> 4);
    float rstd = stats[64 + bg];
    float ga = gamma[c] * rstd;
    float be = beta[c] - stats[bg] * ga;
    const float* xr = x + ((size_t)(b * C_ + c)) * HW_ + n0 + ch * 16;
    #pragma unroll
    for (int i = 0; i < 4; ++i) {
      float4 v = *reinterpret_cast<const float4*>(xr + i * 4);
      int nl = ch * 16 + i * 4;
      lds[cl * 69 + nl + 0] = v.x * ga + be;
      lds[cl * 69 + nl + 1] = v.y * ga + be;
      lds[cl * 69 + nl + 2] = v.z * ga + be;
      lds[cl * 69 + nl + 3] = v.w * ga + be;
    }
  }
  __syncthreads();
  {
    int nl = t >> 2, cw = t & 3;
    unsigned short* orow = tb + ((size_t)(b * HW_ + n0 + nl)) * C_ + c0 + cw * 16;
    #pragma unroll
    for (int i = 0; i < 4; ++i) {
      ushort4 o4;
      o4.x = f2bf(lds[(cw * 16 + i * 4 + 0) * 69 + nl]);
      o4.y = f2bf(lds[(cw * 16 + i * 4 + 1) * 69 + nl]);
      o4.z = f2bf(lds[(cw * 16 + i * 4 + 2) * 69 + nl]);
      o4.w = f2bf(lds[(cw * 16 + i * 4 + 3) * 69 + nl]);
      *reinterpret_cast<ushort4*>(orow + i * 4) = o4;
    }
  }
}

// ---------------- f32 -> bf16 weight cast, all 4 weights in one launch ----------------
__global__ void cast_w4(const float* __restrict__ s0, const float* __restrict__ s1,
                        const float* __restrict__ s2, const float* __restrict__ s3,
                        unsigned short* __restrict__ dst) {
  int which = blockIdx.y;
  const float* src = which == 0 ? s0 : which == 1 ? s1 : which == 2 ? s2 : s3;
  int i = (blockIdx.x * 256 + threadIdx.x) * 4;
  float4 v = *reinterpret_cast<const float4*>(src + i);
  ushort4 o; o.x = f2bf(v.x); o.y = f2bf(v.y); o.z = f2bf(v.z); o.w = f2bf(v.w);
  *reinterpret_cast<ushort4*>(dst + (size_t)which * 262144 + i) = o;
}

// ---------------- C[m][n] = sum_k A[m][k] B[n][k]  (both row-major over k) ----------------
// MODE 0: bf16 out, bias per col (q,k).  MODE 1: bf16 out, bias per row (vT).
// MODE 2: f32 out, bias per row + residual (final proj).
template <int MODE>
__global__ __launch_bounds__(256, 2) void gemm_bt(
    const unsigned short* __restrict__ A, long sA,
    const unsigned short* __restrict__ B, long sB,
    void* __restrict__ Cv, long sC, int M, int N,
    const float* __restrict__ bias,
    const float* __restrict__ resid, long sR) {
  __shared__ unsigned short Al[128 * 72];
  __shared__ unsigned short Bl[128 * 72];
  int z = blockIdx.z;
  const unsigned short* Ab = A + (size_t)z * sA;
  const unsigned short* Bb = B + (size_t)z * sB;
  int n0 = blockIdx.x * 128, m0 = blockIdx.y * 128;
  int t = threadIdx.x, lane = t & 63, w = t >> 6;
  int l15 = lane & 15, quad = lane >> 4;
  int mw = (w & 1) * 64, nw = (w >> 1) * 64;
  f32x4 acc[4][4] = {};
  int r = t >> 1, coff = (t & 1) * 32;
  for (int kc = 0; kc < K_; kc += 64) {
    __syncthreads();
    const unsigned short* As = Ab + (size_t)(m0 + r) * K_ + kc + coff;
    const unsigned short* Bs = Bb + (size_t)(n0 + r) * K_ + kc + coff;
    #pragma unroll
    for (int i = 0; i < 4; ++i) {
      *reinterpret_cast<uint4*>(&Al[r * 72 + coff + i * 8]) = *reinterpret_cast<const uint4*>(As + i * 8);
      *reinterpret_cast<uint4*>(&Bl[r * 72 + coff + i * 8]) = *reinterpret_cast<const uint4*>(Bs + i * 8);
    }
    __syncthreads();
    #pragma unroll
    for (int kk = 0; kk < 2; ++kk) {
      bf16x8 af[4];
      #pragma unroll
      for (int mt = 0; mt < 4; ++mt)
        af[mt] = *reinterpret_cast<const bf16x8*>(&Al[(mw + mt * 16 + l15) * 72 + kk * 32 + quad * 8]);
      #pragma unroll
      for (int nt = 0; nt < 4; ++nt) {
        bf16x8 bfr = *reinterpret_cast<const bf16x8*>(&Bl[(nw + nt * 16 + l15) * 72 + kk * 32 + quad * 8]);
        #pragma unroll
        for (int mt = 0; mt < 4; ++mt)
          acc[mt][nt] = __builtin_amdgcn_mfma_f32_16x16x32_bf16(af[mt], bfr, acc[mt][nt], 0, 0, 0);
      }
    }
  }
  #pragma unroll
  for (int mt = 0; mt < 4; ++mt)
    #pragma unroll
    for (int nt = 0; nt < 4; ++nt)
      #pragma unroll
      for (int rr = 0; rr < 4; ++rr) {
        int row = m0 + mw + mt * 16 + quad * 4 + rr;
        int col = n0 + nw + nt * 16 + l15;
        float v = acc[mt][nt][rr];
        if (MODE == 0) {
          v += bias[col];
          reinterpret_cast<unsigned short*>(Cv)[(size_t)z * sC + (size_t)row * N + col] = f2bf(v);
        } else if (MODE == 1) {
          v += bias[row];
          reinterpret_cast<unsigned short*>(Cv)[(size_t)z * sC + (size_t)row * N + col] = f2bf(v);
        } else {
          v += bias[row];
          v += resid[(size_t)z * sR + (size_t)row * N + col];
          reinterpret_cast<float*>(Cv)[(size_t)z * sC + (size_t)row * N + col] = v;
        }
      }
}

// ---------------- flash attention: Br=64, Bc=128, j-split 4 ----------------
__global__ __launch_bounds__(512, 2) void attn(
    const unsigned short* __restrict__ qg, const unsigned short* __restrict__ kg,
    const unsigned short* __restrict__ vg,  // vT: (b, c, n)
    unsigned short* __restrict__ opart, float* __restrict__ mpart, float* __restrict__ lpart) {
  __shared__ unsigned short KVl[128 * 136];
  __shared__ unsigned short Pl[64 * 136];
  __shared__ float sm_m[64], sm_l[64], sm_alpha[64], sm_red[128];
  int qt = blockIdx.x, jh = blockIdx.y, b = blockIdx.z;
  int t = threadIdx.x, lane = t & 63, w = t >> 6;
  int l15 = lane & 15, quad = lane >> 4;
  int rw = w & 3, cw = w >> 2;
  int m0 = qt * 64;
  if (t < 64) { sm_m[t] = NEG_INF_; sm_l[t] = 0.f; }
  bf16x8 qa[16];
  {
    const unsigned short* qrow = qg + ((size_t)(b * HW_ + m0 + rw * 16 + l15)) * K_ + quad * 8;
    #pragma unroll
    for (int kk = 0; kk < 16; ++kk)
      qa[kk] = *reinterpret_cast<const bf16x8*>(qrow + kk * 32);
  }
  f32x4 acc_o[4][4] = {};
  int sr = t >> 2, scoff = (t & 3) * 32;
  __syncthreads();
  for (int it = 0; it < 8; ++it) {
    int j0 = jh * 1024 + it * 128;
    f32x4 acc_s[4] = {};
    #pragma unroll
    for (int kc = 0; kc < 512; kc += 128) {
      __syncthreads();
      const unsigned short* ks = kg + ((size_t)(b * HW_ + j0 + sr)) * K_ + kc + scoff;
      #pragma unroll
      for (int i = 0; i < 4; ++i)
        *reinterpret_cast<uint4*>(&KVl[sr * 136 + scoff + i * 8]) = *reinterpret_cast<const uint4*>(ks + i * 8);
      __syncthreads();
      #pragma unroll
      for (int kk = 0; kk < 4; ++kk)
        #pragma unroll
        for (int ct = 0; ct < 4; ++ct) {
          bf16x8 bfr = *reinterpret_cast<const bf16x8*>(&KVl[(cw * 64 + ct * 16 + l15) * 136 + kk * 32 + quad * 8]);
          acc_s[ct] = __builtin_amdgcn_mfma_f32_16x16x32_bf16(qa[(kc >> 5) + kk], bfr, acc_s[ct], 0, 0, 0);
        }
    }
    // scale + row max (over this wave's 64 cols)
    float mx[4];
    #pragma unroll
    for (int rr = 0; rr < 4; ++rr) {
      float m = NEG_INF_;
      #pragma unroll
      for (int ct = 0; ct < 4; ++ct) {
        acc_s[ct][rr] *= SCALE_;
        m = fmaxf(m, acc_s[ct][rr]);
      }
      mx[rr] = m;
    }
    #pragma unroll
    for (int off = 1; off < 16; off <<= 1)
      #pragma unroll
      for (int rr = 0; rr < 4; ++rr)
        mx[rr] = fmaxf(mx[rr], __shfl_xor(mx[rr], off));
    if (l15 == 0)
      #pragma unroll
      for (int rr = 0; rr < 4; ++rr)
        sm_red[cw * 64 + rw * 16 + quad * 4 + rr] = mx[rr];
    __syncthreads();
    if (t < 64) {
      float mnew = fmaxf(sm_m[t], fmaxf(sm_red[t], sm_red[64 + t]));
      sm_alpha[t] = __expf(sm_m[t] - mnew);
      sm_m[t] = mnew;
    }
    __syncthreads();
    // P = exp(s - m) -> LDS (bf16) + row sums
    float sum[4] = {0.f, 0.f, 0.f, 0.f};
    #pragma unroll
    for (int ct = 0; ct < 4; ++ct)
      #pragma unroll
      for (int rr = 0; rr < 4; ++rr) {
        int rowl = rw * 16 + quad * 4 + rr;
        float p = __expf(acc_s[ct][rr] - sm_m[rowl]);
        sum[rr] += p;
        Pl[rowl * 136 + cw * 64 + ct * 16 + l15] = f2bf(p);
      }
    #pragma unroll
    for (int off = 1; off < 16; off <<= 1)
      #pragma unroll
      for (int rr = 0; rr < 4; ++rr)
        sum[rr] += __shfl_xor(sum[rr], off);
    if (l15 == 0)
      #pragma unroll
      for (int rr = 0; rr < 4; ++rr)
        sm_red[cw * 64 + rw * 16 + quad * 4 + rr] = sum[rr];
    __syncthreads();
    if (t < 64)
      sm_l[t] = sm_l[t] * sm_alpha[t] + sm_red[t] + sm_red[64 + t];
    // rescale O by alpha
    #pragma unroll
    for (int rr = 0; rr < 4; ++rr) {
      float a = sm_alpha[rw * 16 + quad * 4 + rr];
      #pragma unroll
      for (int dc = 0; dc < 4; ++dc)
        #pragma unroll
        for (int nt = 0; nt < 4; ++nt)
          acc_o[dc][nt][rr] *= a;
    }
    // P A-frags (constant across the dc loop)
    bf16x8 pa[4];
    #pragma unroll
    for (int ksx = 0; ksx < 4; ++ksx)
      pa[ksx] = *reinterpret_cast<const bf16x8*>(&Pl[(rw * 16 + l15) * 136 + ksx * 32 + quad * 8]);
    #pragma unroll
    for (int dc = 0; dc < 4; ++dc) {
      if (dc) __syncthreads();   // dc==0: KVl reads already fenced by softmax barriers
      const unsigned short* vs = vg + ((size_t)(b * K_ + dc * 128 + sr)) * HW_ + j0 + scoff;
      #pragma unroll
      for (int i = 0; i < 4; ++i)
        *reinterpret_cast<uint4*>(&KVl[sr * 136 + scoff + i * 8]) = *reinterpret_cast<const uint4*>(vs + i * 8);
      __syncthreads();
      #pragma unroll
      for (int nt = 0; nt < 4; ++nt)
        #pragma unroll
        for (int ksx = 0; ksx < 4; ++ksx) {
          bf16x8 vb = *reinterpret_cast<const bf16x8*>(&KVl[(cw * 64 + nt * 16 + l15) * 136 + ksx * 32 + quad * 8]);
          acc_o[dc][nt] = __builtin_amdgcn_mfma_f32_16x16x32_bf16(pa[ksx], vb, acc_o[dc][nt], 0, 0, 0);
        }
    }
  }
  // write partials (unnormalized O in bf16, running m and l)
  int part = jh * 2 + b;
  unsigned short* ob = opart + ((size_t)part * HW_ + m0) * 512;
  #pragma unroll
  for (int dc = 0; dc < 4; ++dc)
    #pragma unroll
    for (int nt = 0; nt < 4; ++nt) {
      int d = dc * 128 + cw * 64 + nt * 16 + l15;
      #pragma unroll
      for (int rr = 0; rr < 4; ++rr) {
        int rowl = rw * 16 + quad * 4 + rr;
        ob[(size_t)rowl * 512 + d] = f2bf(acc_o[dc][nt][rr]);
      }
    }
  __syncthreads();
  if (t < 64) {
    mpart[(size_t)part * HW_ + m0 + t] = sm_m[t];
    lpart[(size_t)part * HW_ + m0 + t] = sm_l[t];
  }
}

// ---------------- merge the four j-split quarters ----------------
__global__ void merge_o(const unsigned short* __restrict__ opart, const float* __restrict__ mpart,
                        const float* __restrict__ lpart, unsigned short* __restrict__ om) {
  int rg = blockIdx.x;            // b*4096 + n
  int b = rg >> 12, n = rg & 4095;
  float m[4], l[4], M = NEG_INF_;
  #pragma unroll
  for (int p = 0; p < 4; ++p) {
    size_t r = (size_t)(p * 2 + b) * HW_ + n;
    m[p] = mpart[r]; l[p] = lpart[r];
    M = fmaxf(M, m[p]);
  }
  float wgt[4], L = 0.f;
  #pragma unroll
  for (int p = 0; p < 4; ++p) { wgt[p] = __expf(m[p] - M); L += l[p] * wgt[p]; }
  float inv = 1.f / L;
  unsigned short* orow = om + (size_t)rg * 512;
  for (int d = threadIdx.x; d < 512; d += 256) {
    float acc = 0.f;
    #pragma unroll
    for (int p = 0; p < 4; ++p)
      acc += bf2f(opart[((size_t)(p * 2 + b) * HW_ + n) * 512 + d]) * wgt[p];
    orow[d] = f2bf(acc * inv);
  }
}

extern "C" void kernel_launch(void* const* d_in, const int* in_sizes, int n_in,
                              void* d_out, int out_size, void* d_ws, size_t ws_size,
                              hipStream_t stream) {
  const float* x     = (const float*)d_in[0];
  const float* gamma = (const float*)d_in[1];
  const float* beta  = (const float*)d_in[2];
  const float* wq    = (const float*)d_in[3];
  const float* bq    = (const float*)d_in[4];
  const float* wk    = (const float*)d_in[5];
  const float* bk    = (const float*)d_in[6];
  const float* wv    = (const float*)d_in[7];
  const float* bv    = (const float*)d_in[8];
  const float* wp    = (const float*)d_in[9];
  const float* bp    = (const float*)d_in[10];
  float* out = (float*)d_out;

  char* ws = (char*)d_ws;
  size_t o = 0;
  float* stats          = (float*)(ws + o);          o += 1024;
  unsigned short* tb    = (unsigned short*)(ws + o); o += 8388608;   // om aliases tb after attn
  unsigned short* qb    = (unsigned short*)(ws + o); o += 8388608;
  unsigned short* kb    = (unsigned short*)(ws + o); o += 8388608;
  unsigned short* vTb   = (unsigned short*)(ws + o); o += 8388608;
  unsigned short* wqb   = (unsigned short*)(ws + o); o += 524288;
  unsigned short* wkb   = (unsigned short*)(ws + o); o += 524288;
  unsigned short* wvb   = (unsigned short*)(ws + o); o += 524288;
  unsigned short* wpb   = (unsigned short*)(ws + o); o += 524288;
  unsigned short* opart = (unsigned short*)(ws + o); o += 33554432;  // 8 parts bf16
  float* mpart          = (float*)(ws + o);          o += 131072;
  float* lpart          = (float*)(ws + o);          o += 131072;
  unsigned short* om    = tb;                                        // alias

  gn_stats<<<64, 256, 0, stream>>>(x, stats);
  build_t<<<dim3(64, 8, 2), 256, 0, stream>>>(x, stats, gamma, beta, tb);
  cast_w4<<<dim3(256, 4), 256, 0, stream>>>(wq, wk, wv, wp, wqb);
  // q = t @ wq^T + bq  (M=4096 rows of t, N=512 outputs)
  gemm_bt<0><<<dim3(4, 32, 2), 256, 0, stream>>>(tb, (long)HW_ * K_, wqb, 0, qb, (long)HW_ * K_, HW_, C_, bq, nullptr, 0);
  gemm_bt<0><<<dim3(4, 32, 2), 256, 0, stream>>>(tb, (long)HW_ * K_, wkb, 0, kb, (long)HW_ * K_, HW_, C_, bk, nullptr, 0);
  // vT[o][n] = wv[o][:] . t[n][:] + bv[o]  (M=512, N=4096)
  gemm_bt<1><<<dim3(32, 4, 2), 256, 0, stream>>>(wvb, 0, tb, (long)HW_ * K_, vTb, (long)C_ * HW_, C_, HW_, bv, nullptr, 0);
  attn<<<dim3(64, 4, 2), 512, 0, stream>>>(qb, kb, vTb, opart, mpart, lpart);
  merge_o<<<8192, 256, 0, stream>>>(opart, mpart, lpart, om);
  // out[c][n] = x + wp[c][:] . o[n][:] + bp[c]
  gemm_bt<2><<<dim3(32, 4, 2), 256, 0, stream>>>(wpb, 0, om, (long)HW_ * K_, out, (long)C_ * HW_, C_, HW_, bp, x, (long)C_ * HW_);
}